// Round 7
// baseline (270.272 us; speedup 1.0000x reference)
//
#include <hip/hip_runtime.h>

typedef __attribute__((ext_vector_type(8))) short bf16x8;
typedef __attribute__((ext_vector_type(4))) float f32x4;

#define EPS 1e-5f
#define B 8
#define C 256
#define NPIX 4096      // 64*64
#define NCH 144        // rows: 0..63 q_bn, 64..127 v_bn, 128..143 kf(raw)
#define ROW_V 64
#define ROW_KF 128
#define PAD 11
#define VH_WORDS 3840  // 4-byte words reserved per (v,b) halo (3784 used)

// workspace layout (float offsets)
#define WP_OFF    0u          // Wt transposed: 256*144 = 36864
#define BIAS_OFF  36864u      // 144
#define PROJ_OFF  37120u      // 8*144*4096 = 4718592
#define RMAX_OFF  4755712u    // 128
#define RSC_OFF   4755840u    // 128
#define LC_OFF    4755968u    // 8*16*64 = 8192
#define ET_OFF    4764160u    // E variants: 94208 ushort = 47104 floats
#define QT_OFF    4811264u    // qT: 8*64*4096 = 2097152
#define OUTT_OFF  6908416u    // outT: 8*256*4096 = 8388608 (end 15297024 floats)
#define WS_NEED_QT    6908416u
#define WS_NEED_FULL  15297024u

// ---------------- 1) fold BN into transposed projection weights Wt[c][144] ----------
__global__ __launch_bounds__(256) void k_wfold(
    const float* __restrict__ Wq, const float* __restrict__ qg, const float* __restrict__ qb,
    const float* __restrict__ qm, const float* __restrict__ qv,
    const float* __restrict__ Wk, const float* __restrict__ Wv,
    const float* __restrict__ vg, const float* __restrict__ vb,
    const float* __restrict__ vm, const float* __restrict__ vvar,
    float* __restrict__ Wt, float* __restrict__ biasp) {
  int o = blockIdx.x;   // 0..143
  int t = threadIdx.x;  // 0..255 = c
  const float* src; float s, bias;
  if (o < 64) {
    s = qg[o] * rsqrtf(qv[o] + EPS); bias = qb[o] - qm[o] * s; src = Wq + o * C;
  } else if (o < 128) {
    int i = o - 64;
    s = vg[i] * rsqrtf(vvar[i] + EPS); bias = vb[i] - vm[i] * s; src = Wv + i * C;
  } else {
    int i = o - 128; s = 1.f; bias = 0.f; src = Wk + i * C;
  }
  Wt[t * NCH + o] = src[t] * s;
  if (t == 0) biasp[o] = bias;
}

// ---------------- 1b) build 8 shifted bf16 filter variants (shift lives ONLY here) ----
__global__ __launch_bounds__(256) void k_eprep(
    const float* __restrict__ emb, ushort* __restrict__ etw) {
  int i = blockIdx.x * 256 + threadIdx.x;   // 0..94207
  int s = i / 11776;
  int r = i % 11776;
  int dy = r / 512;
  int l = (r / 8) % 64;
  int jj = r % 8;
  int f = l & 15, q = l >> 4;
  int dx = q * 8 + jj - s;
  float val = (dx >= 0 && dx < 23) ? emb[f * 529 + dy * 23 + dx] : 0.f;
  unsigned u = __float_as_uint(val);
  etw[i] = (ushort)((u + 0x7fffu + ((u >> 16) & 1u)) >> 16);
}

// ---------------- 2) projection GEMM: 16 groups of 9 ch ----------
// Grid (tile, g, b): the 16 g-replicas sharing an x-slice are 16 apart in linear
// block id -> 16 % 8 XCDs == 0 -> same XCD -> x re-reads are L2-local.
// 2048 blocks = 8/CU = 8 waves/SIMD (R4's latency fix, doubled again).
__global__ __launch_bounds__(256) void k_proj(
    const float* __restrict__ x, const float* __restrict__ Wt,
    const float* __restrict__ biasp, float* __restrict__ proj) {
  int tile = blockIdx.x;  // 0..15
  int g = blockIdx.y;     // 0..15 (9 ch each)
  int b = blockIdx.z;
  int t = threadIdx.x;
  int px = tile * 256 + t;
  const float* xb = x + (size_t)b * C * NPIX + px;
  float acc[9];
  #pragma unroll
  for (int i = 0; i < 9; i++) acc[i] = 0.f;
  #pragma unroll 4
  for (int c = 0; c < C; c++) {
    float xv = xb[(size_t)c * NPIX];
    const float* wrow = Wt + c * NCH + g * 9;   // uniform -> s_load
    #pragma unroll
    for (int i = 0; i < 9; i++) acc[i] += xv * wrow[i];
  }
  float* ob = proj + ((size_t)b * NCH + g * 9) * NPIX + px;
  #pragma unroll
  for (int i = 0; i < 9; i++) ob[(size_t)i * NPIX] = acc[i] + biasp[g * 9 + i];
}

// ---------------- 2b) transpose q rows: proj[b][ch][p] -> qT[b][ch][s*512+i] ----------
// p = row*64 + 8g + s ; i = row*8 + g. LDS pad p' = p + (p>>3): conflict-free.
__global__ __launch_bounds__(256) void k_qtrans(
    const float* __restrict__ proj, float* __restrict__ qT) {
  int ch = blockIdx.x, b = blockIdx.y, t = threadIdx.x;
  __shared__ float buf[4608];
  const float* src = proj + ((size_t)b * NCH + ch) * NPIX;
  for (int it = 0; it < 16; it++) {
    int p = it * 256 + t;
    buf[p + (p >> 3)] = src[p];
  }
  __syncthreads();
  float* dst = qT + ((size_t)b * 64 + ch) * NPIX;
  for (int it = 0; it < 16; it++) {
    int idx = it * 256 + t;           // s*512 + i
    int s = idx >> 9, i = idx & 511;
    int p = (i >> 3) * 64 + (i & 7) * 8 + s;
    dst[idx] = buf[p + (p >> 3)];
  }
}

// ---------------- 2c) prebuild bf16 halos: one 86x88 halo per (v,b) ----------------
// Written into the DEAD proj q-row region (q rows are consumed by k_qtrans before
// this runs; mode>=1 conv reads qT, never proj q-rows).
__global__ __launch_bounds__(256) void k_vhalo(
    const float* __restrict__ proj, uint* __restrict__ vhg) {
  int v = blockIdx.x, b = blockIdx.y, t = threadIdx.x;
  const float* vrow = proj + ((size_t)b * NCH + ROW_V + v) * NPIX;
  uint* dst = vhg + (size_t)b * NCH * NPIX + (size_t)v * VH_WORDS;  // words == floats (4B)
  for (int p2 = t; p2 < 3784; p2 += 256) {
    int hr = p2 / 44;           // halo row 0..85
    int hc = (p2 % 44) * 2;     // halo col (even) 0..86
    int ir = hr - 11;
    int ic0 = hc - 11, ic1 = hc - 10;
    bool rok = (ir >= 0 && ir < 64);
    float f0 = (rok && ic0 >= 0 && ic0 < 64) ? vrow[ir * 64 + ic0] : 0.f;
    float f1 = (rok && ic1 >= 0 && ic1 < 64) ? vrow[ir * 64 + ic1] : 0.f;
    uint u0 = __float_as_uint(f0), u1 = __float_as_uint(f1);
    uint h0 = (u0 + 0x7fffu + ((u0 >> 16) & 1u)) >> 16;
    uint h1 = (u1 + 0x7fffu + ((u1 >> 16) & 1u)) >> 16;
    dst[p2] = (h0 & 0xffffu) | (h1 << 16);
  }
}

// ---------------- 3) softmax row stats ----------
__global__ __launch_bounds__(256) void k_softstat(
    const float* __restrict__ proj, float* __restrict__ rmax, float* __restrict__ rsc) {
  int k = blockIdx.x, b = blockIdx.y, t = threadIdx.x;
  const float* row = proj + ((size_t)b * NCH + ROW_KF + k) * NPIX;
  __shared__ float sd[256];
  float m = -1e30f;
  for (int n = t; n < NPIX; n += 256) m = fmaxf(m, row[n]);
  sd[t] = m; __syncthreads();
  for (int s = 128; s > 0; s >>= 1) { if (t < s) sd[t] = fmaxf(sd[t], sd[t + s]); __syncthreads(); }
  m = sd[0]; __syncthreads();
  float sum = 0.f;
  for (int n = t; n < NPIX; n += 256) sum += __expf(row[n] - m);
  sd[t] = sum; __syncthreads();
  for (int s = 128; s > 0; s >>= 1) { if (t < s) sd[t] += sd[t + s]; __syncthreads(); }
  if (t == 0) { rmax[b * 16 + k] = m; rsc[b * 16 + k] = 1.f / sd[0]; }
}

// ---------------- 4) lambda_c partial: atomicAdd into zeroed lc ----------
__global__ __launch_bounds__(256) void k_lambda_c(
    const float* __restrict__ proj, const float* __restrict__ rmax,
    const float* __restrict__ rsc, float* __restrict__ lc) {
  int k = blockIdx.x, chunk = blockIdx.y, b = blockIdx.z, t = threadIdx.x;
  const float* row = proj + ((size_t)b * NCH + ROW_KF + k) * NPIX;
  const float* vbase = proj + ((size_t)b * NCH + ROW_V) * NPIX;
  float m = rmax[b * 16 + k], sc = rsc[b * 16 + k];
  float acc[64];
  #pragma unroll
  for (int i = 0; i < 64; i++) acc[i] = 0.f;
  for (int it = 0; it < 2; ++it) {
    int n = chunk * 512 + it * 256 + t;
    float p = __expf(row[n] - m) * sc;
    #pragma unroll
    for (int vv = 0; vv < 64; vv++) acc[vv] += p * vbase[(size_t)vv * NPIX + n];
  }
  int lane = t & 63, wid = t >> 6;
  float keep = 0.f;
  #pragma unroll
  for (int vv = 0; vv < 64; vv++) {
    float s = acc[vv];
    #pragma unroll
    for (int off = 32; off > 0; off >>= 1) s += __shfl_xor(s, off);
    if (lane == vv) keep = s;
  }
  __shared__ float sh[4 * 64];
  sh[wid * 64 + lane] = keep;
  __syncthreads();
  if (t < 64) {
    float val = sh[t] + sh[64 + t] + sh[128 + t] + sh[192 + t];
    atomicAdd(&lc[((size_t)b * 16 + k) * 64 + t], val);
  }
}

// ---------------- 5) MFMA implicit-im2col conv + fused epilogue (R4 winner) --------
// B-fragment at (dy,tt) equals (dy+2,tt-1): address baseA + (dy+2tt)*11. Hold a
// 16-slot circular register buffer of halo-row fragments (rows dy..dy+15, slot
// (r&1)*8+((r>>1)&7)); each dy reads ONE new fragment instead of eight. Fully
// unrolled dy loop -> all indices static -> pure register renaming, no scratch.
// 256 thr / 4 waves / VGPR ~60: best measured config (R4: 66.5 us). The 512-thr
// 8-wave variant (R5/R6) doubled LDS traffic and lost ~11 us - do not revisit.
__global__ __launch_bounds__(256, 2) void k_conv_mfma(
    const float* __restrict__ proj, const ushort* __restrict__ etw,
    const float* __restrict__ qT, const float* __restrict__ lc,
    const uint* __restrict__ vhg,
    float* __restrict__ outT, float* __restrict__ out, int mode) {
  int s = blockIdx.x;      // 0..7
  int v = blockIdx.y;      // 0..63
  int b = blockIdx.z;
  int t = threadIdx.x;
  __shared__ __align__(16) ushort vh[86 * 88];       // 15136 B halo bf16
  __shared__ __align__(16) ushort elds[23 * 64 * 8]; // 23552 B E_s chunks

  {
    const uint4* src = (const uint4*)etw + s * 1472;
    uint4* dst = (uint4*)elds;
    for (int i = t; i < 1472; i += 256) dst[i] = src[i];
  }
  if (mode != 0) {
    const uint4* vsrc = (const uint4*)(vhg + (size_t)b * NCH * NPIX + (size_t)v * VH_WORDS);
    uint4* vdst = (uint4*)vh;
    for (int i = t; i < 946; i += 256) vdst[i] = vsrc[i];
  } else {
    const float* vrow = proj + ((size_t)b * NCH + ROW_V + v) * NPIX;
    for (int i = t; i < 86 * 88; i += 256) {
      int hr = i / 88, hc = i % 88;
      int ir = hr - 11, ic = hc - 11;
      float val = (ir >= 0 && ir < 64 && ic >= 0 && ic < 64) ? vrow[ir * 64 + ic] : 0.f;
      unsigned u = __float_as_uint(val);
      vh[i] = (ushort)((u + 0x7fffu + ((u >> 16) & 1u)) >> 16);
    }
  }
  __syncthreads();

  int lane = t & 63, w = t >> 6;
  int n_ = lane & 15, q = lane >> 4;
  int rn = n_ >> 3, g = n_ & 7;

  f32x4 acc[8];
  #pragma unroll
  for (int i = 0; i < 8; i++) acc[i] = (f32x4)(0.f);

  const bf16x8* vh8 = (const bf16x8*)vh;
  const bf16x8* e8 = (const bf16x8*)elds;
  int baseA = (w * 16 + rn) * 11 + g + q;

  // prime circular fragment buffer with halo rows 0..15 (relative to baseA)
  bf16x8 bfr[16];
  #pragma unroll
  for (int r = 0; r < 16; r++)
    bfr[(r & 1) * 8 + ((r >> 1) & 7)] = vh8[baseA + r * 11];

  #pragma unroll
  for (int dy = 0; dy < 23; dy++) {
    bf16x8 ef = e8[dy * 64 + lane];
    // issue next row's read early; commit into the slot after this dy's MFMAs
    bf16x8 tmp;
    if (dy + 16 <= 36) tmp = vh8[baseA + (dy + 16) * 11];
    #pragma unroll
    for (int tt = 0; tt < 8; tt++) {
      int r = dy + 2 * tt;
      acc[tt] = __builtin_amdgcn_mfma_f32_16x16x32_bf16(
          ef, bfr[(r & 1) * 8 + ((r >> 1) & 7)], acc[tt], 0, 0, 0);
    }
    if (dy + 16 <= 36) {
      int rr = dy + 16;
      bfr[(rr & 1) * 8 + ((rr >> 1) & 7)] = tmp;
    }
  }

  float lcv[4];
  #pragma unroll
  for (int r = 0; r < 4; r++) lcv[r] = lc[((size_t)b * 16 + q * 4 + r) * 64 + v];

  if (mode != 0) {
    const float* qTb = qT + (size_t)b * 64 * NPIX;
    float* obT = outT + (size_t)b * 256 * NPIX;
    float* ob = out + (size_t)b * 256 * NPIX;
    #pragma unroll
    for (int tt = 0; tt < 8; tt++) {
      int row = w * 16 + 2 * tt + rn;
      int io = s * 512 + row * 8 + g;              // qT / outT index (coalesced)
      float lam[4];
      #pragma unroll
      for (int r = 0; r < 4; r++) lam[r] = acc[tt][r] + lcv[r];
      float y[4];
      #pragma unroll
      for (int h = 0; h < 4; h++) {
        float a = 0.f;
        #pragma unroll
        for (int r = 0; r < 4; r++)
          a += qTb[(size_t)(h * 16 + q * 4 + r) * NPIX + io] * lam[r];
        y[h] = a;
      }
      #pragma unroll
      for (int h = 0; h < 4; h++) {
        y[h] += __shfl_xor(y[h], 16);
        y[h] += __shfl_xor(y[h], 32);
      }
      if (q == 0) {
        if (mode == 2) {
          #pragma unroll
          for (int h = 0; h < 4; h++) obT[(size_t)(h * 64 + v) * NPIX + io] = y[h];
        } else {
          int p = row * 64 + 8 * g + s;
          #pragma unroll
          for (int h = 0; h < 4; h++) ob[(size_t)(h * 64 + v) * NPIX + p] = y[h];
        }
      }
    }
  } else {
    const float* qbp = proj + (size_t)b * NCH * NPIX;
    float* ob = out + (size_t)b * 256 * NPIX;
    #pragma unroll
    for (int tt = 0; tt < 8; tt++) {
      int p = (w * 16 + 2 * tt + rn) * 64 + 8 * g + s;
      float lam[4];
      #pragma unroll
      for (int r = 0; r < 4; r++) lam[r] = acc[tt][r] + lcv[r];
      float y[4];
      #pragma unroll
      for (int h = 0; h < 4; h++) {
        float a = 0.f;
        #pragma unroll
        for (int r = 0; r < 4; r++)
          a += qbp[(size_t)(h * 16 + q * 4 + r) * NPIX + p] * lam[r];
        y[h] = a;
      }
      #pragma unroll
      for (int h = 0; h < 4; h++) {
        y[h] += __shfl_xor(y[h], 16);
        y[h] += __shfl_xor(y[h], 32);
      }
      if (q == 0) {
        #pragma unroll
        for (int h = 0; h < 4; h++) ob[(size_t)(h * 64 + v) * NPIX + p] = y[h];
      }
    }
  }
}

// ---------------- 6) un-transpose: outT[b][ch][s*512+i] -> out[b][ch][p] ----------
__global__ __launch_bounds__(256) void k_outtrans(
    const float* __restrict__ outT, float* __restrict__ out) {
  int ch = blockIdx.x, b = blockIdx.y, t = threadIdx.x;
  __shared__ float buf[4608];
  const float* src = outT + ((size_t)b * 256 + ch) * NPIX;
  for (int it = 0; it < 16; it++) {
    int idx = it * 256 + t;           // s*512 + i
    int s = idx >> 9, i = idx & 511;
    int p = (i >> 3) * 64 + (i & 7) * 8 + s;
    buf[p + (p >> 3)] = src[idx];
  }
  __syncthreads();
  float* dst = out + ((size_t)b * 256 + ch) * NPIX;
  for (int it = 0; it < 16; it++) {
    int p = it * 256 + t;
    dst[p] = buf[p + (p >> 3)];
  }
}

extern "C" void kernel_launch(void* const* d_in, const int* in_sizes, int n_in,
                              void* d_out, int out_size, void* d_ws, size_t ws_size,
                              hipStream_t stream) {
  const float* x    = (const float*)d_in[0];
  const float* Wq   = (const float*)d_in[1];
  const float* qg   = (const float*)d_in[2];
  const float* qbta = (const float*)d_in[3];
  const float* qm   = (const float*)d_in[4];
  const float* qv   = (const float*)d_in[5];
  const float* Wk   = (const float*)d_in[6];
  const float* Wv   = (const float*)d_in[7];
  const float* vg   = (const float*)d_in[8];
  const float* vb   = (const float*)d_in[9];
  const float* vm   = (const float*)d_in[10];
  const float* vvar = (const float*)d_in[11];
  const float* emb  = (const float*)d_in[12];
  float* ws   = (float*)d_ws;
  float* Wt   = ws + WP_OFF;
  float* bp   = ws + BIAS_OFF;
  float* proj = ws + PROJ_OFF;
  float* rmax = ws + RMAX_OFF;
  float* rsc  = ws + RSC_OFF;
  float* lcw  = ws + LC_OFF;
  ushort* etw = (ushort*)(ws + ET_OFF);
  float* qT   = ws + QT_OFF;
  float* outT = ws + OUTT_OFF;
  float* out  = (float*)d_out;
  uint* vhg   = (uint*)proj;   // dead q-row region of proj, reused per (b,v)

  size_t wsf = ws_size / sizeof(float);
  int mode = (wsf >= WS_NEED_FULL) ? 2 : ((wsf >= WS_NEED_QT) ? 1 : 0);

  hipLaunchKernelGGL(k_wfold, dim3(144), dim3(256), 0, stream,
                     Wq, qg, qbta, qm, qv, Wk, Wv, vg, vb, vm, vvar, Wt, bp);
  hipLaunchKernelGGL(k_eprep, dim3(368), dim3(256), 0, stream, emb, etw);
  hipMemsetAsync(lcw, 0, 16 * 64 * B * sizeof(float), stream);
  hipLaunchKernelGGL(k_proj, dim3(16, 16, 8), dim3(256), 0, stream, x, Wt, bp, proj);
  if (mode >= 1) {
    hipLaunchKernelGGL(k_qtrans, dim3(64, 8), dim3(256), 0, stream, proj, qT);
    hipLaunchKernelGGL(k_vhalo, dim3(64, 8), dim3(256), 0, stream, proj, vhg);
  }
  hipLaunchKernelGGL(k_softstat, dim3(16, 8), dim3(256), 0, stream, proj, rmax, rsc);
  hipLaunchKernelGGL(k_lambda_c, dim3(16, 8, 8), dim3(256), 0, stream, proj, rmax, rsc, lcw);
  hipLaunchKernelGGL(k_conv_mfma, dim3(8, 64, 8), dim3(256), 0, stream,
                     proj, etw, qT, lcw, vhg, outT, out, mode);
  if (mode == 2)
    hipLaunchKernelGGL(k_outtrans, dim3(256, 8), dim3(256), 0, stream, outT, out);
}

// Round 8
// 234.707 us; speedup vs baseline: 1.1515x; 1.1515x over previous
//
#include <hip/hip_runtime.h>

typedef __attribute__((ext_vector_type(8))) short bf16x8;
typedef __attribute__((ext_vector_type(4))) float f32x4;

#define EPS 1e-5f
#define B 8
#define C 256
#define NPIX 4096      // 64*64
#define NCH 144        // rows: 0..63 q_bn, 64..127 v_bn, 128..143 kf(raw)
#define ROW_V 64
#define ROW_KF 128
#define PAD 11
#define VH_WORDS 3840  // 4-byte words reserved per (v,b) halo (3784 used)

// workspace layout (float offsets)
#define WP_OFF    0u          // Wt transposed: 256*144 = 36864
#define BIAS_OFF  36864u      // 144
#define PROJ_OFF  37120u      // 8*144*4096 = 4718592
#define RMAX_OFF  4755712u    // 128
#define RSC_OFF   4755840u    // 128
#define LC_OFF    4755968u    // 8*16*64 = 8192
#define ET_OFF    4764160u    // E variants: 94208 ushort = 47104 floats
#define QT_OFF    4811264u    // qT: 8*64*4096 = 2097152
#define OUTT_OFF  6908416u    // outT: 8*256*4096 = 8388608 (end 15297024 floats)
#define WS_NEED_QT    6908416u
#define WS_NEED_FULL  15297024u

__device__ inline short f2bf(float f) {
  unsigned u = __float_as_uint(f);
  return (short)((u + 0x7fffu + ((u >> 16) & 1u)) >> 16);
}

// ---------------- 1) fold BN into transposed projection weights Wt[c][144] ----------
__global__ __launch_bounds__(256) void k_wfold(
    const float* __restrict__ Wq, const float* __restrict__ qg, const float* __restrict__ qb,
    const float* __restrict__ qm, const float* __restrict__ qv,
    const float* __restrict__ Wk, const float* __restrict__ Wv,
    const float* __restrict__ vg, const float* __restrict__ vb,
    const float* __restrict__ vm, const float* __restrict__ vvar,
    float* __restrict__ Wt, float* __restrict__ biasp) {
  int o = blockIdx.x;   // 0..143
  int t = threadIdx.x;  // 0..255 = c
  const float* src; float s, bias;
  if (o < 64) {
    s = qg[o] * rsqrtf(qv[o] + EPS); bias = qb[o] - qm[o] * s; src = Wq + o * C;
  } else if (o < 128) {
    int i = o - 64;
    s = vg[i] * rsqrtf(vvar[i] + EPS); bias = vb[i] - vm[i] * s; src = Wv + i * C;
  } else {
    int i = o - 128; s = 1.f; bias = 0.f; src = Wk + i * C;
  }
  Wt[t * NCH + o] = src[t] * s;
  if (t == 0) biasp[o] = bias;
}

// ---------------- 1b) build 8 shifted bf16 filter variants (shift lives ONLY here) ----
__global__ __launch_bounds__(256) void k_eprep(
    const float* __restrict__ emb, ushort* __restrict__ etw) {
  int i = blockIdx.x * 256 + threadIdx.x;   // 0..94207
  int s = i / 11776;
  int r = i % 11776;
  int dy = r / 512;
  int l = (r / 8) % 64;
  int jj = r % 8;
  int f = l & 15, q = l >> 4;
  int dx = q * 8 + jj - s;
  float val = (dx >= 0 && dx < 23) ? emb[f * 529 + dy * 23 + dx] : 0.f;
  unsigned u = __float_as_uint(val);
  etw[i] = (ushort)((u + 0x7fffu + ((u >> 16) & 1u)) >> 16);
}

// ---------------- 2) projection GEMM: 8 groups of 18 ch (R4 winner) ----------
// Grid (tile, g, b): the 8 g-replicas sharing an x-slice are 16 apart in linear
// block id -> 16 % 8 XCDs == 0 -> same XCD -> x re-reads are L2-local.
// 16x9 (R7) was ~3us slower: load:FMA ratio worsens and x traffic doubles.
__global__ __launch_bounds__(256) void k_proj(
    const float* __restrict__ x, const float* __restrict__ Wt,
    const float* __restrict__ biasp, float* __restrict__ proj) {
  int tile = blockIdx.x;  // 0..15
  int g = blockIdx.y;     // 0..7 (18 ch each)
  int b = blockIdx.z;
  int t = threadIdx.x;
  int px = tile * 256 + t;
  const float* xb = x + (size_t)b * C * NPIX + px;
  float acc[18];
  #pragma unroll
  for (int i = 0; i < 18; i++) acc[i] = 0.f;
  #pragma unroll 4
  for (int c = 0; c < C; c++) {
    float xv = xb[(size_t)c * NPIX];
    const float* wrow = Wt + c * NCH + g * 18;   // uniform -> s_load
    #pragma unroll
    for (int i = 0; i < 18; i++) acc[i] += xv * wrow[i];
  }
  float* ob = proj + ((size_t)b * NCH + g * 18) * NPIX + px;
  #pragma unroll
  for (int i = 0; i < 18; i++) ob[(size_t)i * NPIX] = acc[i] + biasp[g * 18 + i];
}

// ---------------- 2b) transpose q rows: proj[b][ch][p] -> qT[b][ch][s*512+i] ----------
// p = row*64 + 8g + s ; i = row*8 + g. LDS pad p' = p + (p>>3): conflict-free.
__global__ __launch_bounds__(256) void k_qtrans(
    const float* __restrict__ proj, float* __restrict__ qT) {
  int ch = blockIdx.x, b = blockIdx.y, t = threadIdx.x;
  __shared__ float buf[4608];
  const float* src = proj + ((size_t)b * NCH + ch) * NPIX;
  for (int it = 0; it < 16; it++) {
    int p = it * 256 + t;
    buf[p + (p >> 3)] = src[p];
  }
  __syncthreads();
  float* dst = qT + ((size_t)b * 64 + ch) * NPIX;
  for (int it = 0; it < 16; it++) {
    int idx = it * 256 + t;           // s*512 + i
    int s = idx >> 9, i = idx & 511;
    int p = (i >> 3) * 64 + (i & 7) * 8 + s;
    dst[idx] = buf[p + (p >> 3)];
  }
}

// ---------------- 2c) prebuild bf16 halos: one 86x88 halo per (v,b) ----------------
// Written into the DEAD proj q-row region (q rows are consumed by k_qtrans before
// this runs; mode>=1 conv reads qT, never proj q-rows).
__global__ __launch_bounds__(256) void k_vhalo(
    const float* __restrict__ proj, uint* __restrict__ vhg) {
  int v = blockIdx.x, b = blockIdx.y, t = threadIdx.x;
  const float* vrow = proj + ((size_t)b * NCH + ROW_V + v) * NPIX;
  uint* dst = vhg + (size_t)b * NCH * NPIX + (size_t)v * VH_WORDS;  // words == floats (4B)
  for (int p2 = t; p2 < 3784; p2 += 256) {
    int hr = p2 / 44;           // halo row 0..85
    int hc = (p2 % 44) * 2;     // halo col (even) 0..86
    int ir = hr - 11;
    int ic0 = hc - 11, ic1 = hc - 10;
    bool rok = (ir >= 0 && ir < 64);
    float f0 = (rok && ic0 >= 0 && ic0 < 64) ? vrow[ir * 64 + ic0] : 0.f;
    float f1 = (rok && ic1 >= 0 && ic1 < 64) ? vrow[ir * 64 + ic1] : 0.f;
    uint u0 = __float_as_uint(f0), u1 = __float_as_uint(f1);
    uint h0 = (u0 + 0x7fffu + ((u0 >> 16) & 1u)) >> 16;
    uint h1 = (u1 + 0x7fffu + ((u1 >> 16) & 1u)) >> 16;
    dst[p2] = (h0 & 0xffffu) | (h1 << 16);
  }
}

// ---------------- 3) softmax row stats ----------
__global__ __launch_bounds__(256) void k_softstat(
    const float* __restrict__ proj, float* __restrict__ rmax, float* __restrict__ rsc) {
  int k = blockIdx.x, b = blockIdx.y, t = threadIdx.x;
  const float* row = proj + ((size_t)b * NCH + ROW_KF + k) * NPIX;
  __shared__ float sd[256];
  float m = -1e30f;
  for (int n = t; n < NPIX; n += 256) m = fmaxf(m, row[n]);
  sd[t] = m; __syncthreads();
  for (int s = 128; s > 0; s >>= 1) { if (t < s) sd[t] = fmaxf(sd[t], sd[t + s]); __syncthreads(); }
  m = sd[0]; __syncthreads();
  float sum = 0.f;
  for (int n = t; n < NPIX; n += 256) sum += __expf(row[n] - m);
  sd[t] = sum; __syncthreads();
  for (int s = 128; s > 0; s >>= 1) { if (t < s) sd[t] += sd[t + s]; __syncthreads(); }
  if (t == 0) { rmax[b * 16 + k] = m; rsc[b * 16 + k] = 1.f / sd[0]; }
}

// ---------------- 4) lambda_c via MFMA: lc[k][vv] = sum_n P[k][n] * v[vv][n] --------
// A GEMM (M=16, N=64, K=4096 per b) replacing the VALU version whose (k,chunk,b)
// grid re-read each v-slice 16x (≈128 MB L2/L3 traffic). Operand layouts are the
// ones hardware-verified by k_eprep/k_conv_mfma:
//   A: lane holds A[row=lane&15][kk=(lane>>4)*8+j]   (P, computed inline)
//   B: lane holds B[kk=(lane>>4)*8+j][col=lane&15]   (v row, bf16)
//   D: lane holds D[row=(lane>>4)*4+r][col=lane&15]
// Grid (split=64, b=8): each block covers 64 n; wave w owns vv-tile w*16.
// v is read exactly once. One atomicAdd per output per wave.
__global__ __launch_bounds__(256) void k_lambda_c(
    const float* __restrict__ proj, const float* __restrict__ rmax,
    const float* __restrict__ rsc, float* __restrict__ lc) {
  int split = blockIdx.x;  // 0..63
  int b = blockIdx.y;
  int t = threadIdx.x;
  int lane = t & 63, w = t >> 6;
  int kr = lane & 15;       // A row (k) for loads; also B col (vv offset)
  int half = lane >> 4;     // k-dim offset 8*half
  float m = rmax[b * 16 + kr], sc = rsc[b * 16 + kr];
  const float* kfrow = proj + ((size_t)b * NCH + ROW_KF + kr) * NPIX;
  const float* vrow  = proj + ((size_t)b * NCH + ROW_V + w * 16 + kr) * NPIX;
  f32x4 acc = (f32x4)(0.f);
  #pragma unroll
  for (int c = 0; c < 2; c++) {
    int n0 = split * 64 + c * 32 + half * 8;
    float4 fa0 = *(const float4*)(kfrow + n0);
    float4 fa1 = *(const float4*)(kfrow + n0 + 4);
    float4 fb0 = *(const float4*)(vrow + n0);
    float4 fb1 = *(const float4*)(vrow + n0 + 4);
    bf16x8 a, bb;
    a[0] = f2bf(__expf(fa0.x - m) * sc); a[1] = f2bf(__expf(fa0.y - m) * sc);
    a[2] = f2bf(__expf(fa0.z - m) * sc); a[3] = f2bf(__expf(fa0.w - m) * sc);
    a[4] = f2bf(__expf(fa1.x - m) * sc); a[5] = f2bf(__expf(fa1.y - m) * sc);
    a[6] = f2bf(__expf(fa1.z - m) * sc); a[7] = f2bf(__expf(fa1.w - m) * sc);
    bb[0] = f2bf(fb0.x); bb[1] = f2bf(fb0.y); bb[2] = f2bf(fb0.z); bb[3] = f2bf(fb0.w);
    bb[4] = f2bf(fb1.x); bb[5] = f2bf(fb1.y); bb[6] = f2bf(fb1.z); bb[7] = f2bf(fb1.w);
    acc = __builtin_amdgcn_mfma_f32_16x16x32_bf16(a, bb, acc, 0, 0, 0);
  }
  #pragma unroll
  for (int r = 0; r < 4; r++) {
    int k = half * 4 + r;
    atomicAdd(&lc[((size_t)b * 16 + k) * 64 + w * 16 + kr], acc[r]);
  }
}

// ---------------- 5) MFMA implicit-im2col conv + fused epilogue (R4 winner) --------
// B-fragment at (dy,tt) equals (dy+2,tt-1): address baseA + (dy+2tt)*11. Hold a
// 16-slot circular register buffer of halo-row fragments (rows dy..dy+15, slot
// (r&1)*8+((r>>1)&7)); each dy reads ONE new fragment instead of eight. Fully
// unrolled dy loop -> all indices static -> pure register renaming, no scratch.
// 256 thr / 4 waves / VGPR ~60: best measured config (R4: 66.5 us). The 512-thr
// 8-wave variant (R5/R6) doubled LDS traffic and lost ~11 us - do not revisit.
__global__ __launch_bounds__(256, 2) void k_conv_mfma(
    const float* __restrict__ proj, const ushort* __restrict__ etw,
    const float* __restrict__ qT, const float* __restrict__ lc,
    const uint* __restrict__ vhg,
    float* __restrict__ outT, float* __restrict__ out, int mode) {
  int s = blockIdx.x;      // 0..7
  int v = blockIdx.y;      // 0..63
  int b = blockIdx.z;
  int t = threadIdx.x;
  __shared__ __align__(16) ushort vh[86 * 88];       // 15136 B halo bf16
  __shared__ __align__(16) ushort elds[23 * 64 * 8]; // 23552 B E_s chunks

  {
    const uint4* src = (const uint4*)etw + s * 1472;
    uint4* dst = (uint4*)elds;
    for (int i = t; i < 1472; i += 256) dst[i] = src[i];
  }
  if (mode != 0) {
    const uint4* vsrc = (const uint4*)(vhg + (size_t)b * NCH * NPIX + (size_t)v * VH_WORDS);
    uint4* vdst = (uint4*)vh;
    for (int i = t; i < 946; i += 256) vdst[i] = vsrc[i];
  } else {
    const float* vrow = proj + ((size_t)b * NCH + ROW_V + v) * NPIX;
    for (int i = t; i < 86 * 88; i += 256) {
      int hr = i / 88, hc = i % 88;
      int ir = hr - 11, ic = hc - 11;
      float val = (ir >= 0 && ir < 64 && ic >= 0 && ic < 64) ? vrow[ir * 64 + ic] : 0.f;
      unsigned u = __float_as_uint(val);
      vh[i] = (ushort)((u + 0x7fffu + ((u >> 16) & 1u)) >> 16);
    }
  }
  __syncthreads();

  int lane = t & 63, w = t >> 6;
  int n_ = lane & 15, q = lane >> 4;
  int rn = n_ >> 3, g = n_ & 7;

  f32x4 acc[8];
  #pragma unroll
  for (int i = 0; i < 8; i++) acc[i] = (f32x4)(0.f);

  const bf16x8* vh8 = (const bf16x8*)vh;
  const bf16x8* e8 = (const bf16x8*)elds;
  int baseA = (w * 16 + rn) * 11 + g + q;

  // prime circular fragment buffer with halo rows 0..15 (relative to baseA)
  bf16x8 bfr[16];
  #pragma unroll
  for (int r = 0; r < 16; r++)
    bfr[(r & 1) * 8 + ((r >> 1) & 7)] = vh8[baseA + r * 11];

  #pragma unroll
  for (int dy = 0; dy < 23; dy++) {
    bf16x8 ef = e8[dy * 64 + lane];
    // issue next row's read early; commit into the slot after this dy's MFMAs
    bf16x8 tmp;
    if (dy + 16 <= 36) tmp = vh8[baseA + (dy + 16) * 11];
    #pragma unroll
    for (int tt = 0; tt < 8; tt++) {
      int r = dy + 2 * tt;
      acc[tt] = __builtin_amdgcn_mfma_f32_16x16x32_bf16(
          ef, bfr[(r & 1) * 8 + ((r >> 1) & 7)], acc[tt], 0, 0, 0);
    }
    if (dy + 16 <= 36) {
      int rr = dy + 16;
      bfr[(rr & 1) * 8 + ((rr >> 1) & 7)] = tmp;
    }
  }

  float lcv[4];
  #pragma unroll
  for (int r = 0; r < 4; r++) lcv[r] = lc[((size_t)b * 16 + q * 4 + r) * 64 + v];

  if (mode != 0) {
    const float* qTb = qT + (size_t)b * 64 * NPIX;
    float* obT = outT + (size_t)b * 256 * NPIX;
    float* ob = out + (size_t)b * 256 * NPIX;
    #pragma unroll
    for (int tt = 0; tt < 8; tt++) {
      int row = w * 16 + 2 * tt + rn;
      int io = s * 512 + row * 8 + g;              // qT / outT index (coalesced)
      float lam[4];
      #pragma unroll
      for (int r = 0; r < 4; r++) lam[r] = acc[tt][r] + lcv[r];
      float y[4];
      #pragma unroll
      for (int h = 0; h < 4; h++) {
        float a = 0.f;
        #pragma unroll
        for (int r = 0; r < 4; r++)
          a += qTb[(size_t)(h * 16 + q * 4 + r) * NPIX + io] * lam[r];
        y[h] = a;
      }
      #pragma unroll
      for (int h = 0; h < 4; h++) {
        y[h] += __shfl_xor(y[h], 16);
        y[h] += __shfl_xor(y[h], 32);
      }
      if (q == 0) {
        if (mode == 2) {
          #pragma unroll
          for (int h = 0; h < 4; h++) obT[(size_t)(h * 64 + v) * NPIX + io] = y[h];
        } else {
          int p = row * 64 + 8 * g + s;
          #pragma unroll
          for (int h = 0; h < 4; h++) ob[(size_t)(h * 64 + v) * NPIX + p] = y[h];
        }
      }
    }
  } else {
    const float* qbp = proj + (size_t)b * NCH * NPIX;
    float* ob = out + (size_t)b * 256 * NPIX;
    #pragma unroll
    for (int tt = 0; tt < 8; tt++) {
      int p = (w * 16 + 2 * tt + rn) * 64 + 8 * g + s;
      float lam[4];
      #pragma unroll
      for (int r = 0; r < 4; r++) lam[r] = acc[tt][r] + lcv[r];
      float y[4];
      #pragma unroll
      for (int h = 0; h < 4; h++) {
        float a = 0.f;
        #pragma unroll
        for (int r = 0; r < 4; r++)
          a += qbp[(size_t)(h * 16 + q * 4 + r) * NPIX + p] * lam[r];
        y[h] = a;
      }
      #pragma unroll
      for (int h = 0; h < 4; h++) {
        y[h] += __shfl_xor(y[h], 16);
        y[h] += __shfl_xor(y[h], 32);
      }
      if (q == 0) {
        #pragma unroll
        for (int h = 0; h < 4; h++) ob[(size_t)(h * 64 + v) * NPIX + p] = y[h];
      }
    }
  }
}

// ---------------- 6) un-transpose: outT[b][ch][s*512+i] -> out[b][ch][p] ----------
__global__ __launch_bounds__(256) void k_outtrans(
    const float* __restrict__ outT, float* __restrict__ out) {
  int ch = blockIdx.x, b = blockIdx.y, t = threadIdx.x;
  __shared__ float buf[4608];
  const float* src = outT + ((size_t)b * 256 + ch) * NPIX;
  for (int it = 0; it < 16; it++) {
    int idx = it * 256 + t;           // s*512 + i
    int s = idx >> 9, i = idx & 511;
    int p = (i >> 3) * 64 + (i & 7) * 8 + s;
    buf[p + (p >> 3)] = src[idx];
  }
  __syncthreads();
  float* dst = out + ((size_t)b * 256 + ch) * NPIX;
  for (int it = 0; it < 16; it++) {
    int p = it * 256 + t;
    dst[p] = buf[p + (p >> 3)];
  }
}

extern "C" void kernel_launch(void* const* d_in, const int* in_sizes, int n_in,
                              void* d_out, int out_size, void* d_ws, size_t ws_size,
                              hipStream_t stream) {
  const float* x    = (const float*)d_in[0];
  const float* Wq   = (const float*)d_in[1];
  const float* qg   = (const float*)d_in[2];
  const float* qbta = (const float*)d_in[3];
  const float* qm   = (const float*)d_in[4];
  const float* qv   = (const float*)d_in[5];
  const float* Wk   = (const float*)d_in[6];
  const float* Wv   = (const float*)d_in[7];
  const float* vg   = (const float*)d_in[8];
  const float* vb   = (const float*)d_in[9];
  const float* vm   = (const float*)d_in[10];
  const float* vvar = (const float*)d_in[11];
  const float* emb  = (const float*)d_in[12];
  float* ws   = (float*)d_ws;
  float* Wt   = ws + WP_OFF;
  float* bp   = ws + BIAS_OFF;
  float* proj = ws + PROJ_OFF;
  float* rmax = ws + RMAX_OFF;
  float* rsc  = ws + RSC_OFF;
  float* lcw  = ws + LC_OFF;
  ushort* etw = (ushort*)(ws + ET_OFF);
  float* qT   = ws + QT_OFF;
  float* outT = ws + OUTT_OFF;
  float* out  = (float*)d_out;
  uint* vhg   = (uint*)proj;   // dead q-row region of proj, reused per (b,v)

  size_t wsf = ws_size / sizeof(float);
  int mode = (wsf >= WS_NEED_FULL) ? 2 : ((wsf >= WS_NEED_QT) ? 1 : 0);

  hipLaunchKernelGGL(k_wfold, dim3(144), dim3(256), 0, stream,
                     Wq, qg, qbta, qm, qv, Wk, Wv, vg, vb, vm, vvar, Wt, bp);
  hipLaunchKernelGGL(k_eprep, dim3(368), dim3(256), 0, stream, emb, etw);
  hipMemsetAsync(lcw, 0, 16 * 64 * B * sizeof(float), stream);
  hipLaunchKernelGGL(k_proj, dim3(16, 8, 8), dim3(256), 0, stream, x, Wt, bp, proj);
  if (mode >= 1) {
    hipLaunchKernelGGL(k_qtrans, dim3(64, 8), dim3(256), 0, stream, proj, qT);
    hipLaunchKernelGGL(k_vhalo, dim3(64, 8), dim3(256), 0, stream, proj, vhg);
  }
  hipLaunchKernelGGL(k_softstat, dim3(16, 8), dim3(256), 0, stream, proj, rmax, rsc);
  hipLaunchKernelGGL(k_lambda_c, dim3(64, 8), dim3(256), 0, stream, proj, rmax, rsc, lcw);
  hipLaunchKernelGGL(k_conv_mfma, dim3(8, 64, 8), dim3(256), 0, stream,
                     proj, etw, qT, lcw, vhg, outT, out, mode);
  if (mode == 2)
    hipLaunchKernelGGL(k_outtrans, dim3(256, 8), dim3(256), 0, stream, outT, out);
}

// Round 9
// 217.101 us; speedup vs baseline: 1.2449x; 1.0811x over previous
//
#include <hip/hip_runtime.h>

typedef __attribute__((ext_vector_type(8))) short bf16x8;
typedef __attribute__((ext_vector_type(4))) float f32x4;

#define EPS 1e-5f
#define B 8
#define C 256
#define NPIX 4096      // 64*64
#define NCH 144        // rows: 0..63 q_bn, 64..127 v_bn, 128..143 kf(raw)
#define ROW_V 64
#define ROW_KF 128
#define PAD 11
#define VH_WORDS 3840  // 4-byte words reserved per (v,b) halo (3784 used)

// workspace layout (float offsets)
#define WP_OFF    0u          // Wt transposed: 256*144 = 36864
#define BIAS_OFF  36864u      // 144
#define PROJ_OFF  37120u      // 8*144*4096 = 4718592
#define RMAX_OFF  4755712u    // 128
#define RSC_OFF   4755840u    // 128
#define LC_OFF    4755968u    // 8*16*64 = 8192
#define ET_OFF    4764160u    // E variants: 94208 ushort = 47104 floats
#define QT_OFF    4811264u    // qT: 8*64*4096 = 2097152 (WtA borrows its head pre-qtrans)
#define OUTT_OFF  6908416u    // outT: 8*256*4096 = 8388608 (end 15297024 floats)
#define WS_NEED_QT    6908416u
#define WS_NEED_FULL  15297024u

__device__ inline short f2bf(float f) {
  unsigned u = __float_as_uint(f);
  return (short)((u + 0x7fffu + ((u >> 16) & 1u)) >> 16);
}

// ---------------- 1) fold BN into transposed projection weights Wt[c][144] ----------
__global__ __launch_bounds__(256) void k_wfold(
    const float* __restrict__ Wq, const float* __restrict__ qg, const float* __restrict__ qb,
    const float* __restrict__ qm, const float* __restrict__ qv,
    const float* __restrict__ Wk, const float* __restrict__ Wv,
    const float* __restrict__ vg, const float* __restrict__ vb,
    const float* __restrict__ vm, const float* __restrict__ vvar,
    float* __restrict__ Wt, float* __restrict__ biasp) {
  int o = blockIdx.x;   // 0..143
  int t = threadIdx.x;  // 0..255 = c
  const float* src; float s, bias;
  if (o < 64) {
    s = qg[o] * rsqrtf(qv[o] + EPS); bias = qb[o] - qm[o] * s; src = Wq + o * C;
  } else if (o < 128) {
    int i = o - 64;
    s = vg[i] * rsqrtf(vvar[i] + EPS); bias = vb[i] - vm[i] * s; src = Wv + i * C;
  } else {
    int i = o - 128; s = 1.f; bias = 0.f; src = Wk + i * C;
  }
  Wt[t * NCH + o] = src[t] * s;
  if (t == 0) biasp[o] = bias;
}

// ---------------- 1c) prepack Wt into MFMA A-fragment order (bf16) ----------------
// wtA[(mt*8+kt)*64+lane][j] = bf16(Wt[c][m]), c = kt*32+(lane>>4)*8+j, m = mt*16+(lane&15)
__global__ __launch_bounds__(256) void k_wprep(
    const float* __restrict__ Wt, ushort* __restrict__ wtA) {
  int i = blockIdx.x * 256 + threadIdx.x;   // 0..4607
  int mt = i >> 9;
  int rest = i & 511;
  int kt = rest >> 6;
  int lane = rest & 63;
  int m = mt * 16 + (lane & 15);
  int c0 = kt * 32 + (lane >> 4) * 8;
  ushort* dst = wtA + (size_t)i * 8;
  #pragma unroll
  for (int j = 0; j < 8; j++) {
    float v = Wt[(c0 + j) * NCH + m];
    unsigned u = __float_as_uint(v);
    dst[j] = (ushort)((u + 0x7fffu + ((u >> 16) & 1u)) >> 16);
  }
}

// ---------------- 1b) build 8 shifted bf16 filter variants (shift lives ONLY here) ----
__global__ __launch_bounds__(256) void k_eprep(
    const float* __restrict__ emb, ushort* __restrict__ etw) {
  int i = blockIdx.x * 256 + threadIdx.x;   // 0..94207
  int s = i / 11776;
  int r = i % 11776;
  int dy = r / 512;
  int l = (r / 8) % 64;
  int jj = r % 8;
  int f = l & 15, q = l >> 4;
  int dx = q * 8 + jj - s;
  float val = (dx >= 0 && dx < 23) ? emb[f * 529 + dy * 23 + dx] : 0.f;
  unsigned u = __float_as_uint(val);
  etw[i] = (ushort)((u + 0x7fffu + ((u >> 16) & 1u)) >> 16);
}

// ---------------- 2) projection as MFMA GEMM: proj = Wt^T x + bias ----------------
// M=144 (9 tiles), N=4096 (64 px/block, 16/wave), K=256 (8 tiles). x read ONCE
// (vs 8x in the VALU version). A from wtA (L1/L2-hot), B = bf16(x) inline.
__global__ __launch_bounds__(256) void k_projm(
    const float* __restrict__ x, const ushort* __restrict__ wtA,
    const float* __restrict__ biasp, float* __restrict__ proj) {
  int ntile = blockIdx.x;  // 0..63
  int b = blockIdx.y;
  int t = threadIdx.x;
  int lane = t & 63, w = t >> 6;
  int px = ntile * 64 + w * 16 + (lane & 15);
  int kq = lane >> 4;
  const float* xb = x + (size_t)b * C * NPIX + px;
  const bf16x8* A = (const bf16x8*)wtA;
  f32x4 acc[9];
  #pragma unroll
  for (int i = 0; i < 9; i++) acc[i] = (f32x4)(0.f);
  #pragma unroll 2
  for (int kt = 0; kt < 8; kt++) {
    int c0 = kt * 32 + kq * 8;
    bf16x8 bb;
    #pragma unroll
    for (int j = 0; j < 8; j++) bb[j] = f2bf(xb[(size_t)(c0 + j) * NPIX]);
    #pragma unroll
    for (int mt = 0; mt < 9; mt++) {
      bf16x8 a = A[(mt * 8 + kt) * 64 + lane];
      acc[mt] = __builtin_amdgcn_mfma_f32_16x16x32_bf16(a, bb, acc[mt], 0, 0, 0);
    }
  }
  float* pb = proj + (size_t)b * NCH * NPIX + px;
  #pragma unroll
  for (int mt = 0; mt < 9; mt++) {
    #pragma unroll
    for (int r = 0; r < 4; r++) {
      int ch = mt * 16 + kq * 4 + r;
      pb[(size_t)ch * NPIX] = acc[mt][r] + biasp[ch];
    }
  }
}

// ---------------- 2-fallback) VALU projection (mode 0 only) ----------
__global__ __launch_bounds__(256) void k_proj(
    const float* __restrict__ x, const float* __restrict__ Wt,
    const float* __restrict__ biasp, float* __restrict__ proj) {
  int tile = blockIdx.x;  // 0..15
  int g = blockIdx.y;     // 0..7 (18 ch each)
  int b = blockIdx.z;
  int t = threadIdx.x;
  int px = tile * 256 + t;
  const float* xb = x + (size_t)b * C * NPIX + px;
  float acc[18];
  #pragma unroll
  for (int i = 0; i < 18; i++) acc[i] = 0.f;
  #pragma unroll 4
  for (int c = 0; c < C; c++) {
    float xv = xb[(size_t)c * NPIX];
    const float* wrow = Wt + c * NCH + g * 18;   // uniform -> s_load
    #pragma unroll
    for (int i = 0; i < 18; i++) acc[i] += xv * wrow[i];
  }
  float* ob = proj + ((size_t)b * NCH + g * 18) * NPIX + px;
  #pragma unroll
  for (int i = 0; i < 18; i++) ob[(size_t)i * NPIX] = acc[i] + biasp[g * 18 + i];
}

// ---------------- 2b) transpose q rows: proj[b][ch][p] -> qT[b][ch][s*512+i] ----------
// p = row*64 + 8g + s ; i = row*8 + g. LDS pad p' = p + (p>>3): conflict-free.
__global__ __launch_bounds__(256) void k_qtrans(
    const float* __restrict__ proj, float* __restrict__ qT) {
  int ch = blockIdx.x, b = blockIdx.y, t = threadIdx.x;
  __shared__ float buf[4608];
  const float* src = proj + ((size_t)b * NCH + ch) * NPIX;
  for (int it = 0; it < 16; it++) {
    int p = it * 256 + t;
    buf[p + (p >> 3)] = src[p];
  }
  __syncthreads();
  float* dst = qT + ((size_t)b * 64 + ch) * NPIX;
  for (int it = 0; it < 16; it++) {
    int idx = it * 256 + t;           // s*512 + i
    int s = idx >> 9, i = idx & 511;
    int p = (i >> 3) * 64 + (i & 7) * 8 + s;
    dst[idx] = buf[p + (p >> 3)];
  }
}

// ---------------- 2c) prebuild bf16 halos: one 86x88 halo per (v,b) ----------------
// Written into the DEAD proj q-row region (q rows are consumed by k_qtrans before
// this runs; mode>=1 conv reads qT, never proj q-rows).
__global__ __launch_bounds__(256) void k_vhalo(
    const float* __restrict__ proj, uint* __restrict__ vhg) {
  int v = blockIdx.x, b = blockIdx.y, t = threadIdx.x;
  const float* vrow = proj + ((size_t)b * NCH + ROW_V + v) * NPIX;
  uint* dst = vhg + (size_t)b * NCH * NPIX + (size_t)v * VH_WORDS;  // words == floats (4B)
  for (int p2 = t; p2 < 3784; p2 += 256) {
    int hr = p2 / 44;           // halo row 0..85
    int hc = (p2 % 44) * 2;     // halo col (even) 0..86
    int ir = hr - 11;
    int ic0 = hc - 11, ic1 = hc - 10;
    bool rok = (ir >= 0 && ir < 64);
    float f0 = (rok && ic0 >= 0 && ic0 < 64) ? vrow[ir * 64 + ic0] : 0.f;
    float f1 = (rok && ic1 >= 0 && ic1 < 64) ? vrow[ir * 64 + ic1] : 0.f;
    uint u0 = __float_as_uint(f0), u1 = __float_as_uint(f1);
    uint h0 = (u0 + 0x7fffu + ((u0 >> 16) & 1u)) >> 16;
    uint h1 = (u1 + 0x7fffu + ((u1 >> 16) & 1u)) >> 16;
    dst[p2] = (h0 & 0xffffu) | (h1 << 16);
  }
}

// ---------------- 3) softmax row stats ----------
__global__ __launch_bounds__(256) void k_softstat(
    const float* __restrict__ proj, float* __restrict__ rmax, float* __restrict__ rsc) {
  int k = blockIdx.x, b = blockIdx.y, t = threadIdx.x;
  const float* row = proj + ((size_t)b * NCH + ROW_KF + k) * NPIX;
  __shared__ float sd[256];
  float m = -1e30f;
  for (int n = t; n < NPIX; n += 256) m = fmaxf(m, row[n]);
  sd[t] = m; __syncthreads();
  for (int s = 128; s > 0; s >>= 1) { if (t < s) sd[t] = fmaxf(sd[t], sd[t + s]); __syncthreads(); }
  m = sd[0]; __syncthreads();
  float sum = 0.f;
  for (int n = t; n < NPIX; n += 256) sum += __expf(row[n] - m);
  sd[t] = sum; __syncthreads();
  for (int s = 128; s > 0; s >>= 1) { if (t < s) sd[t] += sd[t + s]; __syncthreads(); }
  if (t == 0) { rmax[b * 16 + k] = m; rsc[b * 16 + k] = 1.f / sd[0]; }
}

// ---------------- 4) lambda_c via MFMA: lc[k][vv] = sum_n P[k][n] * v[vv][n] --------
__global__ __launch_bounds__(256) void k_lambda_c(
    const float* __restrict__ proj, const float* __restrict__ rmax,
    const float* __restrict__ rsc, float* __restrict__ lc) {
  int split = blockIdx.x;  // 0..63
  int b = blockIdx.y;
  int t = threadIdx.x;
  int lane = t & 63, w = t >> 6;
  int kr = lane & 15;       // A row (k) for loads; also B col (vv offset)
  int half = lane >> 4;     // k-dim offset 8*half
  float m = rmax[b * 16 + kr], sc = rsc[b * 16 + kr];
  const float* kfrow = proj + ((size_t)b * NCH + ROW_KF + kr) * NPIX;
  const float* vrow  = proj + ((size_t)b * NCH + ROW_V + w * 16 + kr) * NPIX;
  f32x4 acc = (f32x4)(0.f);
  #pragma unroll
  for (int c = 0; c < 2; c++) {
    int n0 = split * 64 + c * 32 + half * 8;
    float4 fa0 = *(const float4*)(kfrow + n0);
    float4 fa1 = *(const float4*)(kfrow + n0 + 4);
    float4 fb0 = *(const float4*)(vrow + n0);
    float4 fb1 = *(const float4*)(vrow + n0 + 4);
    bf16x8 a, bb;
    a[0] = f2bf(__expf(fa0.x - m) * sc); a[1] = f2bf(__expf(fa0.y - m) * sc);
    a[2] = f2bf(__expf(fa0.z - m) * sc); a[3] = f2bf(__expf(fa0.w - m) * sc);
    a[4] = f2bf(__expf(fa1.x - m) * sc); a[5] = f2bf(__expf(fa1.y - m) * sc);
    a[6] = f2bf(__expf(fa1.z - m) * sc); a[7] = f2bf(__expf(fa1.w - m) * sc);
    bb[0] = f2bf(fb0.x); bb[1] = f2bf(fb0.y); bb[2] = f2bf(fb0.z); bb[3] = f2bf(fb0.w);
    bb[4] = f2bf(fb1.x); bb[5] = f2bf(fb1.y); bb[6] = f2bf(fb1.z); bb[7] = f2bf(fb1.w);
    acc = __builtin_amdgcn_mfma_f32_16x16x32_bf16(a, bb, acc, 0, 0, 0);
  }
  #pragma unroll
  for (int r = 0; r < 4; r++) {
    int k = half * 4 + r;
    atomicAdd(&lc[((size_t)b * 16 + k) * 64 + w * 16 + kr], acc[r]);
  }
}

// ---------------- 5) MFMA implicit-im2col conv + fused epilogue (R4 winner) --------
// B-fragment at (dy,tt) equals (dy+2,tt-1): address baseA + (dy+2tt)*11. Hold a
// 16-slot circular register buffer of halo-row fragments; each dy reads ONE new
// fragment instead of eight. 256 thr / 4 waves / VGPR ~60: best measured config.
__global__ __launch_bounds__(256, 2) void k_conv_mfma(
    const float* __restrict__ proj, const ushort* __restrict__ etw,
    const float* __restrict__ qT, const float* __restrict__ lc,
    const uint* __restrict__ vhg,
    float* __restrict__ outT, float* __restrict__ out, int mode) {
  int s = blockIdx.x;      // 0..7
  int v = blockIdx.y;      // 0..63
  int b = blockIdx.z;
  int t = threadIdx.x;
  __shared__ __align__(16) ushort vh[86 * 88];       // 15136 B halo bf16
  __shared__ __align__(16) ushort elds[23 * 64 * 8]; // 23552 B E_s chunks

  {
    const uint4* src = (const uint4*)etw + s * 1472;
    uint4* dst = (uint4*)elds;
    for (int i = t; i < 1472; i += 256) dst[i] = src[i];
  }
  if (mode != 0) {
    const uint4* vsrc = (const uint4*)(vhg + (size_t)b * NCH * NPIX + (size_t)v * VH_WORDS);
    uint4* vdst = (uint4*)vh;
    for (int i = t; i < 946; i += 256) vdst[i] = vsrc[i];
  } else {
    const float* vrow = proj + ((size_t)b * NCH + ROW_V + v) * NPIX;
    for (int i = t; i < 86 * 88; i += 256) {
      int hr = i / 88, hc = i % 88;
      int ir = hr - 11, ic = hc - 11;
      float val = (ir >= 0 && ir < 64 && ic >= 0 && ic < 64) ? vrow[ir * 64 + ic] : 0.f;
      unsigned u = __float_as_uint(val);
      vh[i] = (ushort)((u + 0x7fffu + ((u >> 16) & 1u)) >> 16);
    }
  }
  __syncthreads();

  int lane = t & 63, w = t >> 6;
  int n_ = lane & 15, q = lane >> 4;
  int rn = n_ >> 3, g = n_ & 7;

  f32x4 acc[8];
  #pragma unroll
  for (int i = 0; i < 8; i++) acc[i] = (f32x4)(0.f);

  const bf16x8* vh8 = (const bf16x8*)vh;
  const bf16x8* e8 = (const bf16x8*)elds;
  int baseA = (w * 16 + rn) * 11 + g + q;

  // prime circular fragment buffer with halo rows 0..15 (relative to baseA)
  bf16x8 bfr[16];
  #pragma unroll
  for (int r = 0; r < 16; r++)
    bfr[(r & 1) * 8 + ((r >> 1) & 7)] = vh8[baseA + r * 11];

  #pragma unroll
  for (int dy = 0; dy < 23; dy++) {
    bf16x8 ef = e8[dy * 64 + lane];
    // issue next row's read early; commit into the slot after this dy's MFMAs
    bf16x8 tmp;
    if (dy + 16 <= 36) tmp = vh8[baseA + (dy + 16) * 11];
    #pragma unroll
    for (int tt = 0; tt < 8; tt++) {
      int r = dy + 2 * tt;
      acc[tt] = __builtin_amdgcn_mfma_f32_16x16x32_bf16(
          ef, bfr[(r & 1) * 8 + ((r >> 1) & 7)], acc[tt], 0, 0, 0);
    }
    if (dy + 16 <= 36) {
      int rr = dy + 16;
      bfr[(rr & 1) * 8 + ((rr >> 1) & 7)] = tmp;
    }
  }

  float lcv[4];
  #pragma unroll
  for (int r = 0; r < 4; r++) lcv[r] = lc[((size_t)b * 16 + q * 4 + r) * 64 + v];

  if (mode != 0) {
    const float* qTb = qT + (size_t)b * 64 * NPIX;
    float* obT = outT + (size_t)b * 256 * NPIX;
    float* ob = out + (size_t)b * 256 * NPIX;
    #pragma unroll
    for (int tt = 0; tt < 8; tt++) {
      int row = w * 16 + 2 * tt + rn;
      int io = s * 512 + row * 8 + g;              // qT / outT index (coalesced)
      float lam[4];
      #pragma unroll
      for (int r = 0; r < 4; r++) lam[r] = acc[tt][r] + lcv[r];
      float y[4];
      #pragma unroll
      for (int h = 0; h < 4; h++) {
        float a = 0.f;
        #pragma unroll
        for (int r = 0; r < 4; r++)
          a += qTb[(size_t)(h * 16 + q * 4 + r) * NPIX + io] * lam[r];
        y[h] = a;
      }
      #pragma unroll
      for (int h = 0; h < 4; h++) {
        y[h] += __shfl_xor(y[h], 16);
        y[h] += __shfl_xor(y[h], 32);
      }
      if (q == 0) {
        if (mode == 2) {
          #pragma unroll
          for (int h = 0; h < 4; h++) obT[(size_t)(h * 64 + v) * NPIX + io] = y[h];
        } else {
          int p = row * 64 + 8 * g + s;
          #pragma unroll
          for (int h = 0; h < 4; h++) ob[(size_t)(h * 64 + v) * NPIX + p] = y[h];
        }
      }
    }
  } else {
    const float* qbp = proj + (size_t)b * NCH * NPIX;
    float* ob = out + (size_t)b * 256 * NPIX;
    #pragma unroll
    for (int tt = 0; tt < 8; tt++) {
      int p = (w * 16 + 2 * tt + rn) * 64 + 8 * g + s;
      float lam[4];
      #pragma unroll
      for (int r = 0; r < 4; r++) lam[r] = acc[tt][r] + lcv[r];
      float y[4];
      #pragma unroll
      for (int h = 0; h < 4; h++) {
        float a = 0.f;
        #pragma unroll
        for (int r = 0; r < 4; r++)
          a += qbp[(size_t)(h * 16 + q * 4 + r) * NPIX + p] * lam[r];
        y[h] = a;
      }
      #pragma unroll
      for (int h = 0; h < 4; h++) {
        y[h] += __shfl_xor(y[h], 16);
        y[h] += __shfl_xor(y[h], 32);
      }
      if (q == 0) {
        #pragma unroll
        for (int h = 0; h < 4; h++) ob[(size_t)(h * 64 + v) * NPIX + p] = y[h];
      }
    }
  }
}

// ---------------- 6) un-transpose: outT[b][ch][s*512+i] -> out[b][ch][p] ----------
__global__ __launch_bounds__(256) void k_outtrans(
    const float* __restrict__ outT, float* __restrict__ out) {
  int ch = blockIdx.x, b = blockIdx.y, t = threadIdx.x;
  __shared__ float buf[4608];
  const float* src = outT + ((size_t)b * 256 + ch) * NPIX;
  for (int it = 0; it < 16; it++) {
    int idx = it * 256 + t;           // s*512 + i
    int s = idx >> 9, i = idx & 511;
    int p = (i >> 3) * 64 + (i & 7) * 8 + s;
    buf[p + (p >> 3)] = src[idx];
  }
  __syncthreads();
  float* dst = out + ((size_t)b * 256 + ch) * NPIX;
  for (int it = 0; it < 16; it++) {
    int p = it * 256 + t;
    dst[p] = buf[p + (p >> 3)];
  }
}

extern "C" void kernel_launch(void* const* d_in, const int* in_sizes, int n_in,
                              void* d_out, int out_size, void* d_ws, size_t ws_size,
                              hipStream_t stream) {
  const float* x    = (const float*)d_in[0];
  const float* Wq   = (const float*)d_in[1];
  const float* qg   = (const float*)d_in[2];
  const float* qbta = (const float*)d_in[3];
  const float* qm   = (const float*)d_in[4];
  const float* qv   = (const float*)d_in[5];
  const float* Wk   = (const float*)d_in[6];
  const float* Wv   = (const float*)d_in[7];
  const float* vg   = (const float*)d_in[8];
  const float* vb   = (const float*)d_in[9];
  const float* vm   = (const float*)d_in[10];
  const float* vvar = (const float*)d_in[11];
  const float* emb  = (const float*)d_in[12];
  float* ws   = (float*)d_ws;
  float* Wt   = ws + WP_OFF;
  float* bp   = ws + BIAS_OFF;
  float* proj = ws + PROJ_OFF;
  float* rmax = ws + RMAX_OFF;
  float* rsc  = ws + RSC_OFF;
  float* lcw  = ws + LC_OFF;
  ushort* etw = (ushort*)(ws + ET_OFF);
  float* qT   = ws + QT_OFF;
  float* outT = ws + OUTT_OFF;
  float* out  = (float*)d_out;
  uint* vhg   = (uint*)proj;      // dead q-row region of proj, reused per (b,v)
  ushort* wtA = (ushort*)qT;      // qT region head; consumed before k_qtrans writes

  size_t wsf = ws_size / sizeof(float);
  int mode = (wsf >= WS_NEED_FULL) ? 2 : ((wsf >= WS_NEED_QT) ? 1 : 0);

  hipLaunchKernelGGL(k_wfold, dim3(144), dim3(256), 0, stream,
                     Wq, qg, qbta, qm, qv, Wk, Wv, vg, vb, vm, vvar, Wt, bp);
  hipLaunchKernelGGL(k_eprep, dim3(368), dim3(256), 0, stream, emb, etw);
  hipMemsetAsync(lcw, 0, 16 * 64 * B * sizeof(float), stream);
  if (mode >= 1) {
    hipLaunchKernelGGL(k_wprep, dim3(18), dim3(256), 0, stream, Wt, wtA);
    hipLaunchKernelGGL(k_projm, dim3(64, 8), dim3(256), 0, stream, x, wtA, bp, proj);
    hipLaunchKernelGGL(k_qtrans, dim3(64, 8), dim3(256), 0, stream, proj, qT);
    hipLaunchKernelGGL(k_vhalo, dim3(64, 8), dim3(256), 0, stream, proj, vhg);
  } else {
    hipLaunchKernelGGL(k_proj, dim3(16, 8, 8), dim3(256), 0, stream, x, Wt, bp, proj);
  }
  hipLaunchKernelGGL(k_softstat, dim3(16, 8), dim3(256), 0, stream, proj, rmax, rsc);
  hipLaunchKernelGGL(k_lambda_c, dim3(64, 8), dim3(256), 0, stream, proj, rmax, rsc, lcw);
  hipLaunchKernelGGL(k_conv_mfma, dim3(8, 64, 8), dim3(256), 0, stream,
                     proj, etw, qT, lcw, vhg, outT, out, mode);
  if (mode == 2)
    hipLaunchKernelGGL(k_outtrans, dim3(256, 8), dim3(256), 0, stream, outT, out);
}